// Round 11
// baseline (198.128 us; speedup 1.0000x reference)
//
#include <hip/hip_runtime.h>
#include <math.h>

#define BSZ   2
#define TSEQ  2048
#define CDIM  1024
#define NHEAD 16
#define HDIM  64
#define BT    (BSZ*TSEQ)
#define NQKV  1152   // 1024 q + 64 k + 64 v

typedef __attribute__((ext_vector_type(8))) short short8;
typedef __attribute__((ext_vector_type(4))) float f32x4;
typedef unsigned short u16;
typedef unsigned int   u32;

__device__ __forceinline__ u16 f2b(float f) {
    union { float f; u32 u; } c; c.f = f;
    u32 u = c.u;
    u += 0x7fffu + ((u >> 16) & 1u);   // round-nearest-even
    return (u16)(u >> 16);
}
__device__ __forceinline__ u32 pack2(float lo, float hi) {
    return (u32)f2b(lo) | ((u32)f2b(hi) << 16);
}

// async global->LDS, 16B per lane. LDS dest must be wave-uniform base + lane*16.
__device__ __forceinline__ void async_copy16(const void* g, void* l) {
    __builtin_amdgcn_global_load_lds(
        (__attribute__((address_space(1))) const void*)g,
        (__attribute__((address_space(3))) void*)l,
        16, 0, 0);
}

// ---------------------------------------------------------------------------
__global__ __launch_bounds__(256) void cast_bf16_kernel(
    const float* __restrict__ src, u16* __restrict__ dst, int n4)
{
    int i = blockIdx.x * 256 + threadIdx.x;
    if (i >= n4) return;
    float4 f = ((const float4*)src)[i];
    u16* d = dst + (size_t)i * 4;
    d[0] = f2b(f.x); d[1] = f2b(f.y); d[2] = f2b(f.z); d[3] = f2b(f.w);
}

// ---------------------------------------------------------------------------
// one 64x64 transpose+cast tile: W[K][Nw] fp32 -> Wt[nofs+n][K] bf16
// ---------------------------------------------------------------------------
__device__ __forceinline__ void transpose_tile(
    const float* __restrict__ W, u16* __restrict__ Wt,
    int K, int Nw, int nofs, int bx, int by, float (*T)[65])
{
    const int tid = threadIdx.x;
    const int k0 = by * 64, n0 = bx * 64;
    #pragma unroll
    for (int i = 0; i < 16; ++i) {
        int idx = i * 256 + tid, r = idx >> 6, c = idx & 63;
        T[r][c] = W[(size_t)(k0 + r) * Nw + n0 + c];
    }
    __syncthreads();
    #pragma unroll
    for (int i = 0; i < 16; ++i) {
        int idx = i * 256 + tid, rn = idx >> 6, ck = idx & 63;
        Wt[(size_t)(nofs + n0 + rn) * K + k0 + ck] = f2b(T[ck][rn]);
    }
}

// all weight transposes + bias concat in ONE launch (blockIdx switch)
__global__ __launch_bounds__(256) void prep_kernel(
    const float* __restrict__ Wq, const float* __restrict__ Wk,
    const float* __restrict__ Wv, const float* __restrict__ Wo,
    const float* __restrict__ bq, const float* __restrict__ bk,
    const float* __restrict__ bv,
    u16* __restrict__ Wqkvt, u16* __restrict__ Wot, float* __restrict__ bqkv)
{
    __shared__ float T[64][65];
    const int bid = blockIdx.x;
    if (bid < 256) {
        transpose_tile(Wq, Wqkvt, 1024, 1024, 0, bid & 15, bid >> 4, T);
    } else if (bid < 272) {
        transpose_tile(Wk, Wqkvt, 1024, 64, 1024, 0, bid - 256, T);
    } else if (bid < 288) {
        transpose_tile(Wv, Wqkvt, 1024, 64, 1088, 0, bid - 272, T);
    } else if (bid < 544) {
        int b2 = bid - 288;
        transpose_tile(Wo, Wot, 1024, 1024, 0, b2 & 15, b2 >> 4, T);
    } else {
        for (int i = threadIdx.x; i < NQKV; i += 256)
            bqkv[i] = (i < 1024) ? bq[i] : (i < 1088 ? bk[i - 1024] : bv[i - 1088]);
    }
}

// ---------------------------------------------------------------------------
// one GEMM K-step: read fragments from (AsC,BsC), 8 MFMAs per wave
// ---------------------------------------------------------------------------
__device__ __forceinline__ void gemm_step(
    const u16* __restrict__ AsC, const u16* __restrict__ BsC,
    int wm, int wn, int quad, int ln16, f32x4 (*acc)[4])
{
    short8 af[2], bf[4];
    #pragma unroll
    for (int mt = 0; mt < 2; ++mt)
        af[mt] = *(const short8*)&AsC[(((wm * 2 + mt) * 64) + quad * 16 + ln16) * 8];
    #pragma unroll
    for (int nt = 0; nt < 4; ++nt)
        bf[nt] = *(const short8*)&BsC[(((wn * 4 + nt) * 64) + quad * 16 + ln16) * 8];
    #pragma unroll
    for (int mt = 0; mt < 2; ++mt)
        #pragma unroll
        for (int nt = 0; nt < 4; ++nt)
            acc[mt][nt] = __builtin_amdgcn_mfma_f32_16x16x32_bf16(
                af[mt], bf[nt], acc[mt][nt], 0, 0, 0);
}

// ---------------------------------------------------------------------------
// Fused qkv projection: 64x128 tile, BK=32, 4 waves, DOUBLE-BUFFERED staging
// (stage chunk n+1 right after the barrier -> vmcnt drain hidden under the
// 8 MFMA + 6 ds_read of chunk n). Epilogue: RoPE q (pre-scaled 0.125*log2e),
// RoPE k, transpose v.
// ---------------------------------------------------------------------------
__global__ __launch_bounds__(256) void gemm_qkv_kernel(
    const u16* __restrict__ A, const u16* __restrict__ Bt,
    const float* __restrict__ bias,
    u16* __restrict__ qb, u16* __restrict__ kb, u16* __restrict__ vT)
{
    __shared__ __align__(16) u16 As0[64 * 32],  As1[64 * 32];    // 4+4 KB
    __shared__ __align__(16) u16 Bs0[128 * 32], Bs1[128 * 32];   // 8+8 KB
    const int tid  = threadIdx.x;
    const int wave = tid >> 6, lane = tid & 63;
    const int ln16 = lane & 15, quad = lane >> 4;
    const int wm = wave >> 1, wn = wave & 1;
    const int m0 = blockIdx.y * 64, n0 = blockIdx.x * 128;
    const int K = CDIM;

    const int c_row = ((tid >> 6) << 4) + (tid & 15);
    const int c_k   = ((tid >> 4) & 3) * 8;
    const u16* ag  = &A [(size_t)(m0 + c_row)       * K + c_k];
    const u16* bg0 = &Bt[(size_t)(n0 + c_row)       * K + c_k];
    const u16* bg1 = &Bt[(size_t)(n0 + 64 + c_row)  * K + c_k];
    const int ao = wave * 64 * 8, bo0 = wave * 64 * 8, bo1 = (wave + 4) * 64 * 8;

    f32x4 acc[2][4];
    #pragma unroll
    for (int i = 0; i < 2; ++i)
        #pragma unroll
        for (int j = 0; j < 4; ++j) acc[i][j] = (f32x4){0.f, 0.f, 0.f, 0.f};

    // stage chunk 0 -> buf0
    async_copy16(ag, As0 + ao); async_copy16(bg0, Bs0 + bo0); async_copy16(bg1, Bs0 + bo1);
    ag += 32; bg0 += 32; bg1 += 32;

    int k0 = 0;
    for (;;) {
        __syncthreads();                       // buf0(k0) ready; buf1 free
        if (k0 + 32 < K) {
            async_copy16(ag, As1 + ao); async_copy16(bg0, Bs1 + bo0); async_copy16(bg1, Bs1 + bo1);
            ag += 32; bg0 += 32; bg1 += 32;
        }
        gemm_step(As0, Bs0, wm, wn, quad, ln16, acc);
        k0 += 32;
        if (k0 >= K) break;
        __syncthreads();                       // buf1 ready; buf0 free
        if (k0 + 32 < K) {
            async_copy16(ag, As0 + ao); async_copy16(bg0, Bs0 + bo0); async_copy16(bg1, Bs0 + bo1);
            ag += 32; bg0 += 32; bg1 += 32;
        }
        gemm_step(As1, Bs1, wm, wn, quad, ln16, acc);
        k0 += 32;
        if (k0 >= K) break;
    }

    // ---- bias ----
    #pragma unroll
    for (int mt = 0; mt < 2; ++mt)
        #pragma unroll
        for (int nt = 0; nt < 4; ++nt) {
            float bb = bias[n0 + wn * 64 + nt * 16 + ln16];
            #pragma unroll
            for (int r = 0; r < 4; ++r) acc[mt][nt][r] += bb;
        }

    const int col0 = n0 + wn * 64;   // head-aligned category base
    if (col0 < 1024) {
        // ---- q: rope + (1/8)*log2e scale (flash uses exp2) -> qb ----
        const int hh = col0 >> 6;
        #pragma unroll
        for (int nt = 0; nt < 2; ++nt) {
            int j = nt * 16 + ln16;
            float fr = exp2f(-0.41524101186092029f * (float)j);  // 10000^(-j/32)
            #pragma unroll
            for (int mt = 0; mt < 2; ++mt)
                #pragma unroll
                for (int r = 0; r < 4; ++r) {
                    int m = m0 + wm * 32 + mt * 16 + quad * 4 + r;
                    float sn, cs;
                    __sincosf((float)(m & (TSEQ - 1)) * fr, &sn, &cs);
                    float t1 = acc[mt][nt][r], t2 = acc[mt][nt + 2][r];
                    u16* o = qb + (size_t)m * CDIM + hh * 64 + j;
                    o[0]  = f2b(fmaf(t1, cs,  t2 * sn) * 0.18033688011112043f);
                    o[32] = f2b(fmaf(t1, sn, -t2 * cs) * 0.18033688011112043f);
                }
        }
    } else if (wn == 0) {
        // ---- k: rope -> kb[bt][64] ----
        #pragma unroll
        for (int nt = 0; nt < 2; ++nt) {
            int j = nt * 16 + ln16;
            float fr = exp2f(-0.41524101186092029f * (float)j);
            #pragma unroll
            for (int mt = 0; mt < 2; ++mt)
                #pragma unroll
                for (int r = 0; r < 4; ++r) {
                    int m = m0 + wm * 32 + mt * 16 + quad * 4 + r;
                    float sn, cs;
                    __sincosf((float)(m & (TSEQ - 1)) * fr, &sn, &cs);
                    float t1 = acc[mt][nt][r], t2 = acc[mt][nt + 2][r];
                    u16* o = kb + (size_t)m * HDIM + j;
                    o[0]  = f2b(fmaf(t1, cs,  t2 * sn));
                    o[32] = f2b(fmaf(t1, sn, -t2 * cs));
                }
        }
    } else {
        // ---- v: transpose -> vT[b][d][T] (4 consecutive rows = 8B store) ----
        #pragma unroll
        for (int nt = 0; nt < 4; ++nt) {
            int d = nt * 16 + ln16;
            #pragma unroll
            for (int mt = 0; mt < 2; ++mt) {
                int mr = m0 + wm * 32 + mt * 16 + quad * 4;
                int b  = mr >> 11, tq = mr & (TSEQ - 1);
                uint2 val;
                val.x = pack2(acc[mt][nt][0], acc[mt][nt][1]);
                val.y = pack2(acc[mt][nt][2], acc[mt][nt][3]);
                *(uint2*)&vT[(size_t)(b * HDIM + d) * TSEQ + tq] = val;
            }
        }
    }
}

// ---------------------------------------------------------------------------
// Output projection: Y fp32 = A(bf16) @ Bt(bf16)^T + bias.
// 64x128 tile, BK=32, 4 waves, double-buffered staging (same as qkv).
// ---------------------------------------------------------------------------
__global__ __launch_bounds__(256) void gemm_mfma_kernel(
    const u16* __restrict__ A, const u16* __restrict__ Bt,
    const float* __restrict__ bias, float* __restrict__ Y,
    int M, int N, int K)
{
    __shared__ __align__(16) u16 As0[64 * 32],  As1[64 * 32];    // 4+4 KB
    __shared__ __align__(16) u16 Bs0[128 * 32], Bs1[128 * 32];   // 8+8 KB
    const int tid  = threadIdx.x;
    const int wave = tid >> 6, lane = tid & 63;
    const int ln16 = lane & 15, quad = lane >> 4;
    const int wm = wave >> 1, wn = wave & 1;
    const int m0 = blockIdx.y * 64, n0 = blockIdx.x * 128;

    const int c_row = ((tid >> 6) << 4) + (tid & 15);
    const int c_k   = ((tid >> 4) & 3) * 8;
    const u16* ag  = &A [(size_t)(m0 + c_row)       * K + c_k];
    const u16* bg0 = &Bt[(size_t)(n0 + c_row)       * K + c_k];
    const u16* bg1 = &Bt[(size_t)(n0 + 64 + c_row)  * K + c_k];
    const int ao = wave * 64 * 8, bo0 = wave * 64 * 8, bo1 = (wave + 4) * 64 * 8;

    f32x4 acc[2][4];
    #pragma unroll
    for (int i = 0; i < 2; ++i)
        #pragma unroll
        for (int j = 0; j < 4; ++j) acc[i][j] = (f32x4){0.f, 0.f, 0.f, 0.f};

    async_copy16(ag, As0 + ao); async_copy16(bg0, Bs0 + bo0); async_copy16(bg1, Bs0 + bo1);
    ag += 32; bg0 += 32; bg1 += 32;

    int k0 = 0;
    for (;;) {
        __syncthreads();
        if (k0 + 32 < K) {
            async_copy16(ag, As1 + ao); async_copy16(bg0, Bs1 + bo0); async_copy16(bg1, Bs1 + bo1);
            ag += 32; bg0 += 32; bg1 += 32;
        }
        gemm_step(As0, Bs0, wm, wn, quad, ln16, acc);
        k0 += 32;
        if (k0 >= K) break;
        __syncthreads();
        if (k0 + 32 < K) {
            async_copy16(ag, As0 + ao); async_copy16(bg0, Bs0 + bo0); async_copy16(bg1, Bs0 + bo1);
            ag += 32; bg0 += 32; bg1 += 32;
        }
        gemm_step(As1, Bs1, wm, wn, quad, ln16, acc);
        k0 += 32;
        if (k0 >= K) break;
    }

    #pragma unroll
    for (int mt = 0; mt < 2; ++mt)
        #pragma unroll
        for (int nt = 0; nt < 4; ++nt) {
            int n = n0 + wn * 64 + nt * 16 + ln16;
            float bb = bias[n];
            #pragma unroll
            for (int r = 0; r < 4; ++r) {
                int m = m0 + wm * 32 + mt * 16 + quad * 4 + r;
                Y[(size_t)m * N + n] = acc[mt][nt][r] + bb;
            }
        }
}

// ---------------------------------------------------------------------------
// Flash attention: shift-free softmax, double-buffered K/V with early
// staging (verified R10). Q fragments hoisted to registers (loop-invariant).
// q pre-scaled by 0.125*log2e -> e = exp2(s).
// ---------------------------------------------------------------------------
__device__ __forceinline__ void flash_stage_kv(
    const u16* __restrict__ kb, const u16* __restrict__ vT,
    int b, int kt, u16* __restrict__ Ksb, u16* __restrict__ Vsb,
    const int* row_c, const int* off_c, int c0)
{
    const size_t kt0 = (size_t)(b * TSEQ + kt * 64);
    #pragma unroll
    for (int hf = 0; hf < 2; ++hf) {
        int cc = c0 + hf * 256;
        async_copy16(kb + (kt0 + row_c[hf]) * HDIM + off_c[hf], Ksb + cc * 8);
        async_copy16(vT + (size_t)(b * HDIM + row_c[hf]) * TSEQ + kt * 64 + off_c[hf],
                     Vsb + cc * 8);
    }
}

__device__ __forceinline__ void flash_tile(
    const u16* __restrict__ Ksb, const u16* __restrict__ Vsb,
    const short8* __restrict__ qf, u16* __restrict__ Pw,
    int wave, int ln16, int quad, bool diag,
    float* lsum, f32x4* oacc)
{
    // ---- S = Q.K^T (q pre-scaled by 0.125*log2e) ----
    f32x4 sv[4];
    #pragma unroll
    for (int t = 0; t < 4; ++t) sv[t] = (f32x4){0.f, 0.f, 0.f, 0.f};
    #pragma unroll
    for (int kk2 = 0; kk2 < 2; ++kk2) {
        #pragma unroll
        for (int t = 0; t < 4; ++t) {
            short8 bf = *(const short8*)&Ksb[(t * 128 + kk2 * 64 + quad * 16 + ln16) * 8];
            sv[t] = __builtin_amdgcn_mfma_f32_16x16x32_bf16(qf[kk2], bf, sv[t], 0, 0, 0);
        }
    }

    // ---- e = exp2(s') (0 if masked) ----
    if (diag) {
        #pragma unroll
        for (int t = 0; t < 4; ++t) {
            int key = t * 16 + ln16;
            #pragma unroll
            for (int r = 0; r < 4; ++r) {
                float e = (key > wave * 16 + quad * 4 + r) ? 0.f : exp2f(sv[t][r]);
                lsum[r] += e;
                Pw[(quad * 4 + r) * 72 + t * 16 + ln16] = f2b(e);
            }
        }
    } else {
        #pragma unroll
        for (int t = 0; t < 4; ++t)
            #pragma unroll
            for (int r = 0; r < 4; ++r) {
                float e = exp2f(sv[t][r]);
                lsum[r] += e;
                Pw[(quad * 4 + r) * 72 + t * 16 + ln16] = f2b(e);
            }
    }

    // ---- O += P.V ----
    #pragma unroll
    for (int kk2 = 0; kk2 < 2; ++kk2) {
        short8 pf = *(const short8*)&Pw[ln16 * 72 + kk2 * 32 + quad * 8];
        #pragma unroll
        for (int t = 0; t < 4; ++t) {
            short8 vf = *(const short8*)&Vsb[(t * 128 + kk2 * 64 + quad * 16 + ln16) * 8];
            oacc[t] = __builtin_amdgcn_mfma_f32_16x16x32_bf16(pf, vf, oacc[t], 0, 0, 0);
        }
    }
}

__global__ __launch_bounds__(256) void flash_mfma_kernel(
    const u16* __restrict__ qb, const u16* __restrict__ kb,
    const u16* __restrict__ vT, u16* __restrict__ o)
{
    const int id  = blockIdx.x;
    const int qt  = 31 - (id >> 5);   // longest blocks first (LPT)
    const int hb  = id & 31;
    const int h   = hb >> 1;
    const int b   = hb & 1;
    __shared__ __align__(16) u16 Qs [512 * 8];       // 8 KB
    __shared__ __align__(16) u16 Ks0[512 * 8];       // 8 KB  (double buffer)
    __shared__ __align__(16) u16 Ks1[512 * 8];       // 8 KB
    __shared__ __align__(16) u16 Vs0[512 * 8];       // 8 KB
    __shared__ __align__(16) u16 Vs1[512 * 8];       // 8 KB
    __shared__ __align__(16) u16 Ps[4 * 16 * 72];    // 9 KB, per-wave [16][72]

    const int tid  = threadIdx.x;
    const int wave = tid >> 6, lane = tid & 63;
    const int ln16 = lane & 15, quad = lane >> 4;

    const int c0 = tid;
    int row_c[2], off_c[2];
    #pragma unroll
    for (int hf = 0; hf < 2; ++hf) {
        int c = c0 + hf * 256;
        row_c[hf] = ((c >> 7) << 4) | (c & 15);
        off_c[hf] = ((c >> 6) & 1) * 32 + ((c >> 4) & 3) * 8;
    }

    u16* Pw = &Ps[wave * 16 * 72];

    // ---- stage Q + K/V tile 0 ----
    #pragma unroll
    for (int hf = 0; hf < 2; ++hf)
        async_copy16(
            qb + (size_t)(b * TSEQ + qt * 64 + row_c[hf]) * CDIM + h * HDIM + off_c[hf],
            Qs + (c0 + hf * 256) * 8);
    flash_stage_kv(kb, vT, b, 0, Ks0, Vs0, row_c, off_c, c0);

    float lsum[4];
    f32x4 oacc[4];
    #pragma unroll
    for (int r = 0; r < 4; ++r) lsum[r] = 0.f;
    #pragma unroll
    for (int t = 0; t < 4; ++t) oacc[t] = (f32x4){0.f, 0.f, 0.f, 0.f};

    __syncthreads();          // Q + buf0 ready
    short8 qf[2];             // loop-invariant Q fragments -> registers
    qf[0] = *(const short8*)&Qs[(wave * 128 +  0 + quad * 16 + ln16) * 8];
    qf[1] = *(const short8*)&Qs[(wave * 128 + 64 + quad * 16 + ln16) * 8];

    int kt = 0;
    for (;;) {
        if (kt < qt) flash_stage_kv(kb, vT, b, kt + 1, Ks1, Vs1, row_c, off_c, c0);
        flash_tile(Ks0, Vs0, qf, Pw, wave, ln16, quad, kt == qt, lsum, oacc);
        if (++kt > qt) break;
        __syncthreads();      // buf1 staged; all waves done reading buf0
        if (kt < qt) flash_stage_kv(kb, vT, b, kt + 1, Ks0, Vs0, row_c, off_c, c0);
        flash_tile(Ks1, Vs1, qf, Pw, wave, ln16, quad, kt == qt, lsum, oacc);
        if (++kt > qt) break;
        __syncthreads();      // buf0 staged; all waves done reading buf1
    }

    // ---- epilogue: one 16-lane reduction per row, then O / l ----
    float inv[4];
    #pragma unroll
    for (int r = 0; r < 4; ++r) {
        float l = lsum[r];
        #pragma unroll
        for (int off = 1; off < 16; off <<= 1)
            l += __shfl_xor(l, off, 64);
        inv[r] = 1.0f / l;
    }
    #pragma unroll
    for (int t = 0; t < 4; ++t) {
        #pragma unroll
        for (int r = 0; r < 4; ++r) {
            int row = qt * 64 + wave * 16 + quad * 4 + r;
            int d   = t * 16 + ln16;
            o[(size_t)(b * TSEQ + row) * CDIM + h * HDIM + d] = f2b(oacc[t][r] * inv[r]);
        }
    }
}

// ---------------------------------------------------------------------------
extern "C" void kernel_launch(void* const* d_in, const int* in_sizes, int n_in,
                              void* d_out, int out_size, void* d_ws, size_t ws_size,
                              hipStream_t stream)
{
    const float* x  = (const float*)d_in[0];
    const float* Wq = (const float*)d_in[1];
    const float* bq = (const float*)d_in[2];
    const float* Wk = (const float*)d_in[3];
    const float* bk = (const float*)d_in[4];
    const float* Wv = (const float*)d_in[5];
    const float* bv = (const float*)d_in[6];
    const float* Wo = (const float*)d_in[7];
    const float* bo = (const float*)d_in[8];
    float* out = (float*)d_out;

    const size_t MB = 1u << 20;
    char* w = (char*)d_ws;
    u16*   xb   = (u16*)(w);                   //  8 MB [BT][1024] bf16
    u16*   aob  = (u16*)(w);                   //  alias: xb dead after qkv GEMM
    u16*   qb   = (u16*)(w + 8 * MB);          //  8 MB [BT][1024] rope'd, scaled
    u16*   kb   = (u16*)(w + 16 * MB);         //  0.5 MB [BT][64]
    u16*   vT   = (u16*)(w + 16 * MB + 512 * 1024);   // 0.5 MB [B][64][T]
    u16*   Wqkvt= (u16*)(w + 17 * MB);         //  2.25 MB [1152][1024]
    u16*   Wot  = (u16*)(w + 20 * MB);         //  2 MB
    float* bqkv = (float*)(w + 22 * MB);       //  4.5 KB

    // 1) x -> bf16
    cast_bf16_kernel<<<dim3(BT * CDIM / 4 / 256), dim3(256), 0, stream>>>(
        x, xb, BT * CDIM / 4);
    // 2) all weight transposes + bias concat, one launch
    prep_kernel<<<dim3(545), dim3(256), 0, stream>>>(Wq, Wk, Wv, Wo, bq, bk, bv,
                                                     Wqkvt, Wot, bqkv);
    // 3) fused qkv projection + rope + v-transpose -> qb, kb, vT (bf16)
    gemm_qkv_kernel<<<dim3(NQKV / 128, BT / 64), dim3(256), 0, stream>>>(
        xb, Wqkvt, bqkv, qb, kb, vT);
    // 4) flash attention -> aob (overwrites dead xb)
    flash_mfma_kernel<<<dim3(32 * NHEAD * BSZ), dim3(256), 0, stream>>>(
        qb, kb, vT, aob);
    // 5) output projection
    gemm_mfma_kernel<<<dim3(CDIM / 128, BT / 64), dim3(256), 0, stream>>>(
        aob, Wot, bo, out, BT, CDIM, CDIM);
}

// Round 12
// 192.265 us; speedup vs baseline: 1.0305x; 1.0305x over previous
//
#include <hip/hip_runtime.h>
#include <math.h>

#define BSZ   2
#define TSEQ  2048
#define CDIM  1024
#define NHEAD 16
#define HDIM  64
#define BT    (BSZ*TSEQ)
#define NQKV  1152   // 1024 q + 64 k + 64 v

typedef __attribute__((ext_vector_type(8))) short short8;
typedef __attribute__((ext_vector_type(4))) float f32x4;
typedef unsigned short u16;
typedef unsigned int   u32;

__device__ __forceinline__ u16 f2b(float f) {
    union { float f; u32 u; } c; c.f = f;
    u32 u = c.u;
    u += 0x7fffu + ((u >> 16) & 1u);   // round-nearest-even
    return (u16)(u >> 16);
}
__device__ __forceinline__ u32 pack2(float lo, float hi) {
    return (u32)f2b(lo) | ((u32)f2b(hi) << 16);
}

// async global->LDS, 16B per lane. LDS dest must be wave-uniform base + lane*16.
__device__ __forceinline__ void async_copy16(const void* g, void* l) {
    __builtin_amdgcn_global_load_lds(
        (__attribute__((address_space(1))) const void*)g,
        (__attribute__((address_space(3))) void*)l,
        16, 0, 0);
}

// ---------------------------------------------------------------------------
// one 64x64 transpose+cast tile: W[K][Nw] fp32 -> Wt[nofs+n][K] bf16
// ---------------------------------------------------------------------------
__device__ __forceinline__ void transpose_tile(
    const float* __restrict__ W, u16* __restrict__ Wt,
    int K, int Nw, int nofs, int bx, int by, float (*T)[65])
{
    const int tid = threadIdx.x;
    const int k0 = by * 64, n0 = bx * 64;
    #pragma unroll
    for (int i = 0; i < 16; ++i) {
        int idx = i * 256 + tid, r = idx >> 6, c = idx & 63;
        T[r][c] = W[(size_t)(k0 + r) * Nw + n0 + c];
    }
    __syncthreads();
    #pragma unroll
    for (int i = 0; i < 16; ++i) {
        int idx = i * 256 + tid, rn = idx >> 6, ck = idx & 63;
        Wt[(size_t)(nofs + n0 + rn) * K + k0 + ck] = f2b(T[ck][rn]);
    }
}

// x-cast + all weight transposes + bias concat in ONE launch (blockIdx switch)
__global__ __launch_bounds__(256) void prep_kernel(
    const float* __restrict__ x,
    const float* __restrict__ Wq, const float* __restrict__ Wk,
    const float* __restrict__ Wv, const float* __restrict__ Wo,
    const float* __restrict__ bq, const float* __restrict__ bk,
    const float* __restrict__ bv,
    u16* __restrict__ xb,
    u16* __restrict__ Wqkvt, u16* __restrict__ Wot, float* __restrict__ bqkv)
{
    __shared__ float T[64][65];
    const int bid = blockIdx.x;
    if (bid < 4096) {
        // x -> bf16, 4 elems/thread (4096 blocks x 1024 elems)
        int i = bid * 256 + threadIdx.x;
        float4 f = ((const float4*)x)[i];
        u16* d = xb + (size_t)i * 4;
        d[0] = f2b(f.x); d[1] = f2b(f.y); d[2] = f2b(f.z); d[3] = f2b(f.w);
    } else if (bid < 4352) {
        int b2 = bid - 4096;
        transpose_tile(Wq, Wqkvt, 1024, 1024, 0, b2 & 15, b2 >> 4, T);
    } else if (bid < 4368) {
        transpose_tile(Wk, Wqkvt, 1024, 64, 1024, 0, bid - 4352, T);
    } else if (bid < 4384) {
        transpose_tile(Wv, Wqkvt, 1024, 64, 1088, 0, bid - 4368, T);
    } else if (bid < 4640) {
        int b2 = bid - 4384;
        transpose_tile(Wo, Wot, 1024, 1024, 0, b2 & 15, b2 >> 4, T);
    } else {
        for (int i = threadIdx.x; i < NQKV; i += 256)
            bqkv[i] = (i < 1024) ? bq[i] : (i < 1088 ? bk[i - 1024] : bv[i - 1088]);
    }
}

// ---------------------------------------------------------------------------
// Fused qkv projection (R8 config — measured best): 64x128 tile, BK=32,
// 4 waves (2x2), single-buffered staging (dbuf measured neutral — m99/m100).
// Epilogue: RoPE q (pre-scaled 0.125*log2e so flash uses exp2), RoPE k,
// transpose v.
// ---------------------------------------------------------------------------
__global__ __launch_bounds__(256) void gemm_qkv_kernel(
    const u16* __restrict__ A, const u16* __restrict__ Bt,
    const float* __restrict__ bias,
    u16* __restrict__ qb, u16* __restrict__ kb, u16* __restrict__ vT)
{
    __shared__ __align__(16) u16 AsC[64 * 32];    // 4 KB
    __shared__ __align__(16) u16 BsC[128 * 32];   // 8 KB
    const int tid  = threadIdx.x;
    const int wave = tid >> 6, lane = tid & 63;
    const int ln16 = lane & 15, quad = lane >> 4;
    const int wm = wave >> 1, wn = wave & 1;
    const int m0 = blockIdx.y * 64, n0 = blockIdx.x * 128;
    const int K = CDIM;

    const int c_row = ((tid >> 6) << 4) + (tid & 15);
    const int c_k   = ((tid >> 4) & 3) * 8;
    const u16* ag  = &A [(size_t)(m0 + c_row)       * K + c_k];
    const u16* bg0 = &Bt[(size_t)(n0 + c_row)       * K + c_k];
    const u16* bg1 = &Bt[(size_t)(n0 + 64 + c_row)  * K + c_k];
    u16* a_l  = &AsC[(size_t)wave * 64 * 8];
    u16* b_l0 = &BsC[(size_t)wave * 64 * 8];
    u16* b_l1 = &BsC[(size_t)(wave + 4) * 64 * 8];

    f32x4 acc[2][4];
    #pragma unroll
    for (int i = 0; i < 2; ++i)
        #pragma unroll
        for (int j = 0; j < 4; ++j) acc[i][j] = (f32x4){0.f, 0.f, 0.f, 0.f};

    for (int k0 = 0; k0 < K; k0 += 32) {
        async_copy16(ag,  a_l);
        async_copy16(bg0, b_l0);
        async_copy16(bg1, b_l1);
        ag += 32; bg0 += 32; bg1 += 32;
        __syncthreads();

        short8 af[2], bf[4];
        #pragma unroll
        for (int mt = 0; mt < 2; ++mt)
            af[mt] = *(const short8*)&AsC[(((wm * 2 + mt) * 64) + quad * 16 + ln16) * 8];
        #pragma unroll
        for (int nt = 0; nt < 4; ++nt)
            bf[nt] = *(const short8*)&BsC[(((wn * 4 + nt) * 64) + quad * 16 + ln16) * 8];
        #pragma unroll
        for (int mt = 0; mt < 2; ++mt)
            #pragma unroll
            for (int nt = 0; nt < 4; ++nt)
                acc[mt][nt] = __builtin_amdgcn_mfma_f32_16x16x32_bf16(
                    af[mt], bf[nt], acc[mt][nt], 0, 0, 0);
        __syncthreads();
    }

    // ---- bias ----
    #pragma unroll
    for (int mt = 0; mt < 2; ++mt)
        #pragma unroll
        for (int nt = 0; nt < 4; ++nt) {
            float bb = bias[n0 + wn * 64 + nt * 16 + ln16];
            #pragma unroll
            for (int r = 0; r < 4; ++r) acc[mt][nt][r] += bb;
        }

    const int col0 = n0 + wn * 64;   // head-aligned category base
    if (col0 < 1024) {
        // ---- q: rope + (1/8)*log2e scale (flash uses exp2) -> qb ----
        const int hh = col0 >> 6;
        #pragma unroll
        for (int nt = 0; nt < 2; ++nt) {
            int j = nt * 16 + ln16;
            float fr = exp2f(-0.41524101186092029f * (float)j);  // 10000^(-j/32)
            #pragma unroll
            for (int mt = 0; mt < 2; ++mt)
                #pragma unroll
                for (int r = 0; r < 4; ++r) {
                    int m = m0 + wm * 32 + mt * 16 + quad * 4 + r;
                    float sn, cs;
                    __sincosf((float)(m & (TSEQ - 1)) * fr, &sn, &cs);
                    float t1 = acc[mt][nt][r], t2 = acc[mt][nt + 2][r];
                    u16* o = qb + (size_t)m * CDIM + hh * 64 + j;
                    o[0]  = f2b(fmaf(t1, cs,  t2 * sn) * 0.18033688011112043f);
                    o[32] = f2b(fmaf(t1, sn, -t2 * cs) * 0.18033688011112043f);
                }
        }
    } else if (wn == 0) {
        // ---- k: rope -> kb[bt][64] ----
        #pragma unroll
        for (int nt = 0; nt < 2; ++nt) {
            int j = nt * 16 + ln16;
            float fr = exp2f(-0.41524101186092029f * (float)j);
            #pragma unroll
            for (int mt = 0; mt < 2; ++mt)
                #pragma unroll
                for (int r = 0; r < 4; ++r) {
                    int m = m0 + wm * 32 + mt * 16 + quad * 4 + r;
                    float sn, cs;
                    __sincosf((float)(m & (TSEQ - 1)) * fr, &sn, &cs);
                    float t1 = acc[mt][nt][r], t2 = acc[mt][nt + 2][r];
                    u16* o = kb + (size_t)m * HDIM + j;
                    o[0]  = f2b(fmaf(t1, cs,  t2 * sn));
                    o[32] = f2b(fmaf(t1, sn, -t2 * cs));
                }
        }
    } else {
        // ---- v: transpose -> vT[b][d][T] (4 consecutive rows = 8B store) ----
        #pragma unroll
        for (int nt = 0; nt < 4; ++nt) {
            int d = nt * 16 + ln16;
            #pragma unroll
            for (int mt = 0; mt < 2; ++mt) {
                int mr = m0 + wm * 32 + mt * 16 + quad * 4;
                int b  = mr >> 11, tq = mr & (TSEQ - 1);
                uint2 val;
                val.x = pack2(acc[mt][nt][0], acc[mt][nt][1]);
                val.y = pack2(acc[mt][nt][2], acc[mt][nt][3]);
                *(uint2*)&vT[(size_t)(b * HDIM + d) * TSEQ + tq] = val;
            }
        }
    }
}

// ---------------------------------------------------------------------------
// Output projection (R8 config): Y fp32 = A(bf16) @ Bt(bf16)^T + bias.
// 64x128 tile, BK=32, 4 waves (2x2), single-buffered, chunk-ordered LDS.
// ---------------------------------------------------------------------------
__global__ __launch_bounds__(256) void gemm_mfma_kernel(
    const u16* __restrict__ A, const u16* __restrict__ Bt,
    const float* __restrict__ bias, float* __restrict__ Y,
    int M, int N, int K)
{
    __shared__ __align__(16) u16 AsC[64 * 32];    // 4 KB
    __shared__ __align__(16) u16 BsC[128 * 32];   // 8 KB
    const int tid  = threadIdx.x;
    const int wave = tid >> 6, lane = tid & 63;
    const int ln16 = lane & 15, quad = lane >> 4;
    const int wm = wave >> 1, wn = wave & 1;
    const int m0 = blockIdx.y * 64, n0 = blockIdx.x * 128;

    const int c_row = ((tid >> 6) << 4) + (tid & 15);
    const int c_k   = ((tid >> 4) & 3) * 8;
    const u16* ag  = &A [(size_t)(m0 + c_row)       * K + c_k];
    const u16* bg0 = &Bt[(size_t)(n0 + c_row)       * K + c_k];
    const u16* bg1 = &Bt[(size_t)(n0 + 64 + c_row)  * K + c_k];
    u16* a_l  = &AsC[(size_t)wave * 64 * 8];
    u16* b_l0 = &BsC[(size_t)wave * 64 * 8];
    u16* b_l1 = &BsC[(size_t)(wave + 4) * 64 * 8];

    f32x4 acc[2][4];
    #pragma unroll
    for (int i = 0; i < 2; ++i)
        #pragma unroll
        for (int j = 0; j < 4; ++j) acc[i][j] = (f32x4){0.f, 0.f, 0.f, 0.f};

    for (int k0 = 0; k0 < K; k0 += 32) {
        async_copy16(ag,  a_l);
        async_copy16(bg0, b_l0);
        async_copy16(bg1, b_l1);
        ag += 32; bg0 += 32; bg1 += 32;
        __syncthreads();

        short8 af[2], bf[4];
        #pragma unroll
        for (int mt = 0; mt < 2; ++mt)
            af[mt] = *(const short8*)&AsC[(((wm * 2 + mt) * 64) + quad * 16 + ln16) * 8];
        #pragma unroll
        for (int nt = 0; nt < 4; ++nt)
            bf[nt] = *(const short8*)&BsC[(((wn * 4 + nt) * 64) + quad * 16 + ln16) * 8];
        #pragma unroll
        for (int mt = 0; mt < 2; ++mt)
            #pragma unroll
            for (int nt = 0; nt < 4; ++nt)
                acc[mt][nt] = __builtin_amdgcn_mfma_f32_16x16x32_bf16(
                    af[mt], bf[nt], acc[mt][nt], 0, 0, 0);
        __syncthreads();
    }

    #pragma unroll
    for (int mt = 0; mt < 2; ++mt)
        #pragma unroll
        for (int nt = 0; nt < 4; ++nt) {
            int n = n0 + wn * 64 + nt * 16 + ln16;
            float bb = bias[n];
            #pragma unroll
            for (int r = 0; r < 4; ++r) {
                int m = m0 + wm * 32 + mt * 16 + quad * 4 + r;
                Y[(size_t)m * N + n] = acc[mt][nt][r] + bb;
            }
        }
}

// ---------------------------------------------------------------------------
// Flash attention (R10 structure — measured best 48.6us): shift-free softmax,
// double-buffered K/V with early staging, Q read from LDS each tile (hoist
// regressed in R11). P stored TRUNCATED (bits>>16) with lsum accumulated from
// the same truncated value -> softmax ratio stays consistent, ~2 fewer VALU
// insts per score on the 52%-busy VALU pipe.
// q pre-scaled by 0.125*log2e -> e = exp2(s).
// ---------------------------------------------------------------------------
__device__ __forceinline__ void flash_stage_kv(
    const u16* __restrict__ kb, const u16* __restrict__ vT,
    int b, int kt, u16* __restrict__ Ksb, u16* __restrict__ Vsb,
    const int* row_c, const int* off_c, int c0)
{
    const size_t kt0 = (size_t)(b * TSEQ + kt * 64);
    #pragma unroll
    for (int hf = 0; hf < 2; ++hf) {
        int cc = c0 + hf * 256;
        async_copy16(kb + (kt0 + row_c[hf]) * HDIM + off_c[hf], Ksb + cc * 8);
        async_copy16(vT + (size_t)(b * HDIM + row_c[hf]) * TSEQ + kt * 64 + off_c[hf],
                     Vsb + cc * 8);
    }
}

__device__ __forceinline__ void flash_tile(
    const u16* __restrict__ Ksb, const u16* __restrict__ Vsb,
    const u16* __restrict__ Qs, u16* __restrict__ Pw,
    int wave, int ln16, int quad, bool diag,
    float* lsum, f32x4* oacc)
{
    // ---- S = Q.K^T ----
    f32x4 sv[4];
    #pragma unroll
    for (int t = 0; t < 4; ++t) sv[t] = (f32x4){0.f, 0.f, 0.f, 0.f};
    #pragma unroll
    for (int kk2 = 0; kk2 < 2; ++kk2) {
        short8 af = *(const short8*)&Qs[(wave * 128 + kk2 * 64 + quad * 16 + ln16) * 8];
        #pragma unroll
        for (int t = 0; t < 4; ++t) {
            short8 bf = *(const short8*)&Ksb[(t * 128 + kk2 * 64 + quad * 16 + ln16) * 8];
            sv[t] = __builtin_amdgcn_mfma_f32_16x16x32_bf16(af, bf, sv[t], 0, 0, 0);
        }
    }

    // ---- e = exp2(s') (0 if masked); truncated bf16, consistent lsum ----
    if (diag) {
        #pragma unroll
        for (int t = 0; t < 4; ++t) {
            int key = t * 16 + ln16;
            #pragma unroll
            for (int r = 0; r < 4; ++r) {
                float e = (key > wave * 16 + quad * 4 + r) ? 0.f : exp2f(sv[t][r]);
                u32 bits = __float_as_uint(e);
                lsum[r] += __uint_as_float(bits & 0xffff0000u);
                Pw[(quad * 4 + r) * 72 + t * 16 + ln16] = (u16)(bits >> 16);
            }
        }
    } else {
        #pragma unroll
        for (int t = 0; t < 4; ++t)
            #pragma unroll
            for (int r = 0; r < 4; ++r) {
                float e = exp2f(sv[t][r]);
                u32 bits = __float_as_uint(e);
                lsum[r] += __uint_as_float(bits & 0xffff0000u);
                Pw[(quad * 4 + r) * 72 + t * 16 + ln16] = (u16)(bits >> 16);
            }
    }

    // ---- O += P.V ----
    #pragma unroll
    for (int kk2 = 0; kk2 < 2; ++kk2) {
        short8 pf = *(const short8*)&Pw[ln16 * 72 + kk2 * 32 + quad * 8];
        #pragma unroll
        for (int t = 0; t < 4; ++t) {
            short8 vf = *(const short8*)&Vsb[(t * 128 + kk2 * 64 + quad * 16 + ln16) * 8];
            oacc[t] = __builtin_amdgcn_mfma_f32_16x16x32_bf16(pf, vf, oacc[t], 0, 0, 0);
        }
    }
}

__global__ __launch_bounds__(256) void flash_mfma_kernel(
    const u16* __restrict__ qb, const u16* __restrict__ kb,
    const u16* __restrict__ vT, u16* __restrict__ o)
{
    const int id  = blockIdx.x;
    const int qt  = 31 - (id >> 5);   // longest blocks first (LPT)
    const int hb  = id & 31;
    const int h   = hb >> 1;
    const int b   = hb & 1;
    __shared__ __align__(16) u16 Qs [512 * 8];       // 8 KB
    __shared__ __align__(16) u16 Ks0[512 * 8];       // 8 KB  (double buffer)
    __shared__ __align__(16) u16 Ks1[512 * 8];       // 8 KB
    __shared__ __align__(16) u16 Vs0[512 * 8];       // 8 KB
    __shared__ __align__(16) u16 Vs1[512 * 8];       // 8 KB
    __shared__ __align__(16) u16 Ps[4 * 16 * 72];    // 9 KB, per-wave [16][72]

    const int tid  = threadIdx.x;
    const int wave = tid >> 6, lane = tid & 63;
    const int ln16 = lane & 15, quad = lane >> 4;

    const int c0 = tid;
    int row_c[2], off_c[2];
    #pragma unroll
    for (int hf = 0; hf < 2; ++hf) {
        int c = c0 + hf * 256;
        row_c[hf] = ((c >> 7) << 4) | (c & 15);
        off_c[hf] = ((c >> 6) & 1) * 32 + ((c >> 4) & 3) * 8;
    }

    u16* Pw = &Ps[wave * 16 * 72];

    // ---- stage Q + K/V tile 0 ----
    #pragma unroll
    for (int hf = 0; hf < 2; ++hf)
        async_copy16(
            qb + (size_t)(b * TSEQ + qt * 64 + row_c[hf]) * CDIM + h * HDIM + off_c[hf],
            Qs + (c0 + hf * 256) * 8);
    flash_stage_kv(kb, vT, b, 0, Ks0, Vs0, row_c, off_c, c0);

    float lsum[4];
    f32x4 oacc[4];
    #pragma unroll
    for (int r = 0; r < 4; ++r) lsum[r] = 0.f;
    #pragma unroll
    for (int t = 0; t < 4; ++t) oacc[t] = (f32x4){0.f, 0.f, 0.f, 0.f};

    int kt = 0;
    while (true) {
        __syncthreads();    // buf0 for kt ready; all waves done reading buf1
        if (kt < qt) flash_stage_kv(kb, vT, b, kt + 1, Ks1, Vs1, row_c, off_c, c0);
        flash_tile(Ks0, Vs0, Qs, Pw, wave, ln16, quad, kt == qt, lsum, oacc);
        if (++kt > qt) break;
        __syncthreads();    // buf1 for kt ready; all waves done reading buf0
        if (kt < qt) flash_stage_kv(kb, vT, b, kt + 1, Ks0, Vs0, row_c, off_c, c0);
        flash_tile(Ks1, Vs1, Qs, Pw, wave, ln16, quad, kt == qt, lsum, oacc);
        if (++kt > qt) break;
    }

    // ---- epilogue: one 16-lane reduction per row, then O / l ----
    float inv[4];
    #pragma unroll
    for (int r = 0; r < 4; ++r) {
        float l = lsum[r];
        #pragma unroll
        for (int off = 1; off < 16; off <<= 1)
            l += __shfl_xor(l, off, 64);
        inv[r] = 1.0f / l;
    }
    #pragma unroll
    for (int t = 0; t < 4; ++t) {
        #pragma unroll
        for (int r = 0; r < 4; ++r) {
            int row = qt * 64 + wave * 16 + quad * 4 + r;
            int d   = t * 16 + ln16;
            o[(size_t)(b * TSEQ + row) * CDIM + h * HDIM + d] = f2b(oacc[t][r] * inv[r]);
        }
    }
}

// ---------------------------------------------------------------------------
extern "C" void kernel_launch(void* const* d_in, const int* in_sizes, int n_in,
                              void* d_out, int out_size, void* d_ws, size_t ws_size,
                              hipStream_t stream)
{
    const float* x  = (const float*)d_in[0];
    const float* Wq = (const float*)d_in[1];
    const float* bq = (const float*)d_in[2];
    const float* Wk = (const float*)d_in[3];
    const float* bk = (const float*)d_in[4];
    const float* Wv = (const float*)d_in[5];
    const float* bv = (const float*)d_in[6];
    const float* Wo = (const float*)d_in[7];
    const float* bo = (const float*)d_in[8];
    float* out = (float*)d_out;

    const size_t MB = 1u << 20;
    char* w = (char*)d_ws;
    u16*   xb   = (u16*)(w);                   //  8 MB [BT][1024] bf16
    u16*   aob  = (u16*)(w);                   //  alias: xb dead after qkv GEMM
    u16*   qb   = (u16*)(w + 8 * MB);          //  8 MB [BT][1024] rope'd, scaled
    u16*   kb   = (u16*)(w + 16 * MB);         //  0.5 MB [BT][64]
    u16*   vT   = (u16*)(w + 16 * MB + 512 * 1024);   // 0.5 MB [B][64][T]
    u16*   Wqkvt= (u16*)(w + 17 * MB);         //  2.25 MB [1152][1024]
    u16*   Wot  = (u16*)(w + 20 * MB);         //  2 MB
    float* bqkv = (float*)(w + 22 * MB);       //  4.5 KB

    // 1) x-cast + weight transposes + bias concat, one launch
    prep_kernel<<<dim3(4641), dim3(256), 0, stream>>>(
        x, Wq, Wk, Wv, Wo, bq, bk, bv, xb, Wqkvt, Wot, bqkv);
    // 2) fused qkv projection + rope + v-transpose -> qb, kb, vT (bf16)
    gemm_qkv_kernel<<<dim3(NQKV / 128, BT / 64), dim3(256), 0, stream>>>(
        xb, Wqkvt, bqkv, qb, kb, vT);
    // 3) flash attention -> aob (overwrites dead xb)
    flash_mfma_kernel<<<dim3(32 * NHEAD * BSZ), dim3(256), 0, stream>>>(
        qb, kb, vT, aob);
    // 4) output projection
    gemm_mfma_kernel<<<dim3(CDIM / 128, BT / 64), dim3(256), 0, stream>>>(
        aob, Wot, bo, out, BT, CDIM, CDIM);
}